// Round 5
// baseline (3748.840 us; speedup 1.0000x reference)
//
#include <hip/hip_runtime.h>

// PositionLinear + ReLU: out[t,:] = relu(W @ x[t,:] + b)
// x: [1M][64] f32, W: [64][64] f32, b: [64], out: [1M][64] f32.
// HBM floor ~536 MB @ 6.3 TB/s => ~85 us. FMA floor 8.6 GFLOP @ 157 TF => ~55 us.
//
// Round 5: round 4 was LDS-pipe-bound (24.6K ds_read_b128/CU ~= 123 us; W
// re-read from LDS at 1.5 B/FMA). Fix: W goes WAVE-UNIFORM -> scalar s_load
// pipe (parallel to VALU, K$-resident 16 KB); x goes lane-private: each
// thread holds its token's 64 inputs in VGPRs, loaded once per batch via 16
// conflict-free swizzled ds_read_b128. LDS traffic drops 12x (~10 us).
//   wave w: lane = token (thalf = w&1 selects rows 0-63 / 64-127),
//           output half = (w>>1)*32 (uniform per wave -> scalar W/bias).
// Staging identical to round 4 (coalesced global_load_lds, XOR-swizzled
// per-lane SOURCE address, linear LDS dest; read applies same involution).
// Stores issued AFTER the barrier so the per-batch vmcnt(0) only drains the
// stage loads; stores complete under the next batch's compute.

#define NDIM    64
#define TOKENS  (1u << 20)
#define BTOK    128                  // tokens per batch per block
#define NBATCH  (TOKENS / BTOK)      // 8192
#define XBUF_F  (BTOK * NDIM)        // 8192 floats = 32 KB per buffer
#define GRIDX   512                  // 2 blocks/CU (LDS-capped)
#define NB_PER  (NBATCH / GRIDX)     // 16 batches per block

__device__ __forceinline__ void gload_lds16(const float* gsrc, float* ldst) {
    // dest = ldst + lane*16B (wave-uniform base); gsrc is per-lane.
    __builtin_amdgcn_global_load_lds(
        (const __attribute__((address_space(1))) void*)gsrc,
        (__attribute__((address_space(3))) void*)ldst,
        16, 0, 0);
}

__global__ __launch_bounds__(256, 2) void poslin_relu_kernel(
    const float* __restrict__ x,
    const float* __restrict__ W,
    const float* __restrict__ bias,
    float* __restrict__ out)
{
    __shared__ float xb[2 * XBUF_F];    // 64 KB: x double buffer

    const int tid   = threadIdx.x;
    const int wv    = tid >> 6;
    const int lane  = tid & 63;
    const int thalf = wv & 1;           // token half: rows 0-63 or 64-127
    const int obase = (wv >> 1) * 32;   // output half: uniform per wave

    // Staging: wave wv fills rows [wv*32, +32) = 16B-slots [wv*512, +512).
    // LDS slot (r,s) <- global chunk (r, s ^ (r&7)); read un-swizzles.
    const int slot0 = wv * 512 + lane;
    auto stage = [&](unsigned bi, int bufidx) {
        const float* xsrc = x + (size_t)bi * (BTOK * NDIM);
#pragma unroll
        for (int q = 0; q < 8; ++q) {
            const int slot  = slot0 + q * 64;
            const int r     = slot >> 4;
            const int s     = slot & 15;
            const int chunk = (r << 4) + (s ^ (r & 7));
            gload_lds16(xsrc + 4 * chunk,
                        &xb[(size_t)bufidx * XBUF_F + (wv * 512 + q * 64) * 4]);
        }
    };

    // Prologue: stage first batch.
    stage(blockIdx.x, 0);
    asm volatile("s_waitcnt vmcnt(0)" ::: "memory");
    __syncthreads();

    const int r = thalf * 64 + lane;    // this thread's row within the batch

    int cur = 0;
    for (unsigned m = 0; m < NB_PER; ++m) {
        const unsigned bi = blockIdx.x + m * GRIDX;

        if (m + 1 < NB_PER)
            stage(blockIdx.x + (m + 1) * GRIDX, cur ^ 1);  // hides under compute

        // ---- x row -> 64 VGPRs: 16 swizzled ds_read_b128, conflict-free ----
        const float* xs = &xb[(size_t)cur * XBUF_F];
        float xv[NDIM];
#pragma unroll
        for (int q = 0; q < 16; ++q) {
            const float4 v = *reinterpret_cast<const float4*>(
                xs + r * NDIM + ((q ^ (r & 7)) << 2));
            xv[4 * q + 0] = v.x;
            xv[4 * q + 1] = v.y;
            xv[4 * q + 2] = v.z;
            xv[4 * q + 3] = v.w;
        }

        // ---- 32 outputs = 2 chunks of 16; W/bias indices wave-uniform ----
        auto chunk = [&](float* A, int ob) {
#pragma unroll
            for (int o = 0; o < 16; ++o) A[o] = bias[ob + o];
#pragma unroll
            for (int og = 0; og < 4; ++og) {
                const float* w0 = W + (size_t)(ob + og * 4 + 0) * NDIM;
                const float* w1 = W + (size_t)(ob + og * 4 + 1) * NDIM;
                const float* w2 = W + (size_t)(ob + og * 4 + 2) * NDIM;
                const float* w3 = W + (size_t)(ob + og * 4 + 3) * NDIM;
#pragma unroll
                for (int k = 0; k < NDIM; ++k) {  // const index into xv
                    const float xk = xv[k];
                    A[og * 4 + 0] = fmaf(xk, w0[k], A[og * 4 + 0]);
                    A[og * 4 + 1] = fmaf(xk, w1[k], A[og * 4 + 1]);
                    A[og * 4 + 2] = fmaf(xk, w2[k], A[og * 4 + 2]);
                    A[og * 4 + 3] = fmaf(xk, w3[k], A[og * 4 + 3]);
                }
            }
        };

        float a0[16], a1[16];
        chunk(a0, obase);
        chunk(a1, obase + 16);

        // Stage loads done? (only the 8 gload_lds + prev-iter stores are on
        // vmcnt; prev stores are a full batch old.)
        asm volatile("s_waitcnt vmcnt(0)" ::: "memory");
        __syncthreads();   // buffer cur may now be overwritten next iter

        // ---- ReLU + store AFTER barrier: overlaps next batch's compute.
        // 8 back-to-back dwordx4 per lane = 128 B contiguous, full sectors.
        const size_t t = (size_t)bi * BTOK + r;
        float* op = out + t * NDIM + obase;
#pragma unroll
        for (int c = 0; c < 4; ++c) {
            float4 v;
            v.x = fmaxf(a0[4 * c + 0], 0.0f);
            v.y = fmaxf(a0[4 * c + 1], 0.0f);
            v.z = fmaxf(a0[4 * c + 2], 0.0f);
            v.w = fmaxf(a0[4 * c + 3], 0.0f);
            reinterpret_cast<float4*>(op)[c] = v;
        }
#pragma unroll
        for (int c = 0; c < 4; ++c) {
            float4 v;
            v.x = fmaxf(a1[4 * c + 0], 0.0f);
            v.y = fmaxf(a1[4 * c + 1], 0.0f);
            v.z = fmaxf(a1[4 * c + 2], 0.0f);
            v.w = fmaxf(a1[4 * c + 3], 0.0f);
            reinterpret_cast<float4*>(op + 16)[c] = v;
        }

        cur ^= 1;
    }
}

extern "C" void kernel_launch(void* const* d_in, const int* in_sizes, int n_in,
                              void* d_out, int out_size, void* d_ws, size_t ws_size,
                              hipStream_t stream) {
    const float* x    = (const float*)d_in[0];
    const float* W    = (const float*)d_in[1];
    const float* bias = (const float*)d_in[2];
    float* out        = (float*)d_out;

    poslin_relu_kernel<<<GRIDX, 256, 0, stream>>>(x, W, bias, out);
}

// Round 6
// 446.445 us; speedup vs baseline: 8.3971x; 8.3971x over previous
//
#include <hip/hip_runtime.h>

// PositionLinear + ReLU: out[t,:] = relu(W @ x[t,:] + b)
// x: [1M][64] f32, W: [64][64] f32, b: [64], out: [1M][64] f32.
// HBM floor ~536 MB @ ~6.5 TB/s => ~82 us. FMA floor 8.6 GFLOP @ 157 TF => ~55 us.
//
// Round 6 = round 5's idea with its two bugs fixed:
//  BUG1 (spill -> 7.9 GB scratch FETCH): lambda took float* to local arrays +
//    >128 live floats. Now: only xv[64] (const-indexed) + 4 named scalar
//    accumulators per og-group; ~96 VGPR peak.
//  BUG2 (W not scalarized): obase was threadIdx-derived (divergent to LLVM).
//    Now: one wave per block, each thread does ALL 64 outputs; every W/bias
//    index derives from loop constants only -> provably uniform -> s_load
//    through K$ (16 KB, cache-resident), parallel to the VALU.
//  Single-wave blocks: NO __syncthreads; counted-vmcnt pipeline (T4):
//    stage(next) -> vmcnt(32) [drains the 16 oldest = this batch's loads,
//    leaves next stage + prev stores in flight] -> compute -> 16 stores.
//  LDS per FMA drops 12x vs round 4 (16 ds_read_b128 per thread-batch).
//  BTOK=64 -> 32 KB LDS/block -> 5 blocks/CU (160 KB exactly), grid 1280.

#define NDIM    64
#define TOKENS  (1u << 20)
#define BTOK    64                    // tokens per batch (= block threads)
#define NBATCH  (TOKENS / BTOK)       // 16384
#define XBUF_F  (BTOK * NDIM)         // 4096 floats = 16 KB per buffer
#define GRIDX   1280                  // 5 blocks/CU

__device__ __forceinline__ void gload_lds16(const float* gsrc, float* ldst) {
    // LDS dest = ldst + lane*16B (wave-uniform base); gsrc is per-lane.
    __builtin_amdgcn_global_load_lds(
        (const __attribute__((address_space(1))) void*)gsrc,
        (__attribute__((address_space(3))) void*)ldst,
        16, 0, 0);
}

__global__ __launch_bounds__(64, 1) void poslin_relu_kernel(
    const float* __restrict__ x,
    const float* __restrict__ W,
    const float* __restrict__ bias,
    float* __restrict__ out)
{
    __shared__ float xb[2 * XBUF_F];   // 32 KB double buffer

    const int lane = threadIdx.x;      // one wave per block

    // Stage one 16 KB batch: 16 x global_load_lds_dwordx4.
    // LDS slot s (linear) <- global 16B-chunk (r<<4) + (p ^ (r&7)),
    // r = s>>4, p = s&15 (XOR involution lives in the SOURCE address).
    auto stage = [&](unsigned bi, int buf) {
        const float* xsrc = x + (size_t)bi * (BTOK * NDIM);
        float* ldst = &xb[(size_t)buf * XBUF_F];
#pragma unroll
        for (int q = 0; q < 16; ++q) {
            const int slot  = q * 64 + lane;
            const int r     = slot >> 4;
            const int p     = slot & 15;
            const int chunk = (r << 4) + (p ^ (r & 7));
            gload_lds16(xsrc + 4 * chunk, ldst + q * 256);
        }
    };

    // Prologue: stage first batch, drain once.
    stage(blockIdx.x, 0);
    asm volatile("s_waitcnt vmcnt(0)" ::: "memory");

    int cur = 0;
    for (unsigned bi = blockIdx.x; bi < NBATCH; bi += GRIDX) {
        const unsigned nxt = bi + GRIDX;
        if (nxt < NBATCH) {
            stage(nxt, cur ^ 1);
            // Outstanding (oldest first): loads(cur)=16, stores(prev)<=16,
            // loads(nxt)=16. Waiting to <=32 retires loads(cur) (in-order).
            asm volatile("s_waitcnt vmcnt(32)" ::: "memory");
        } else {
            // No new stage: loads(cur)=16 oldest + stores(prev)<=16.
            asm volatile("s_waitcnt vmcnt(16)" ::: "memory");
        }

        // ---- x row -> 64 VGPRs: 16 swizzled ds_read_b128 (read applies the
        // same involution; banks balanced across all 8 groups). ----
        const float* xs = &xb[(size_t)cur * XBUF_F];
        float xv[NDIM];
#pragma unroll
        for (int q = 0; q < 16; ++q) {
            const float4 v = *reinterpret_cast<const float4*>(
                xs + lane * NDIM + ((q ^ (lane & 7)) << 2));
            xv[4 * q + 0] = v.x;
            xv[4 * q + 1] = v.y;
            xv[4 * q + 2] = v.z;
            xv[4 * q + 3] = v.w;
        }

        // ---- 64 outputs in 16 groups of 4; og partially rolled to keep the
        // hot body I$-small while giving the scheduler room to prefetch the
        // next group's W s_loads. All W/bias indices uniform (og is scalar).
        float* op = out + ((size_t)bi * BTOK + lane) * NDIM;
#pragma unroll 4
        for (int og = 0; og < 16; ++og) {
            const float* __restrict__ w0 = W + (size_t)(og * 4 + 0) * NDIM;
            const float* __restrict__ w1 = W + (size_t)(og * 4 + 1) * NDIM;
            const float* __restrict__ w2 = W + (size_t)(og * 4 + 2) * NDIM;
            const float* __restrict__ w3 = W + (size_t)(og * 4 + 3) * NDIM;
            float a0 = bias[og * 4 + 0];
            float a1 = bias[og * 4 + 1];
            float a2 = bias[og * 4 + 2];
            float a3 = bias[og * 4 + 3];
#pragma unroll
            for (int k = 0; k < NDIM; ++k) {   // const index into xv
                const float xk = xv[k];
                a0 = fmaf(xk, w0[k], a0);
                a1 = fmaf(xk, w1[k], a1);
                a2 = fmaf(xk, w2[k], a2);
                a3 = fmaf(xk, w3[k], a3);
            }
            float4 v;
            v.x = fmaxf(a0, 0.0f);
            v.y = fmaxf(a1, 0.0f);
            v.z = fmaxf(a2, 0.0f);
            v.w = fmaxf(a3, 0.0f);
            *reinterpret_cast<float4*>(op + og * 4) = v;   // 16 stores/batch
        }

        cur ^= 1;
    }
}

extern "C" void kernel_launch(void* const* d_in, const int* in_sizes, int n_in,
                              void* d_out, int out_size, void* d_ws, size_t ws_size,
                              hipStream_t stream) {
    const float* x    = (const float*)d_in[0];
    const float* W    = (const float*)d_in[1];
    const float* bias = (const float*)d_in[2];
    float* out        = (float*)d_out;

    poslin_relu_kernel<<<GRIDX, BTOK, 0, stream>>>(x, W, bias, out);
}

// Round 7
// 271.162 us; speedup vs baseline: 13.8251x; 1.6464x over previous
//
#include <hip/hip_runtime.h>

// PositionLinear + ReLU: out[t,:] = relu(W @ x[t,:] + b)
// x: [1M][64] f32, W: [64][64] f32, b: [64], out: [1M][64] f32.
// HBM floor ~536 MB @ ~6.3 TB/s => ~85 us. FMA floor 8.6 GFLOP @ 157 TF => ~55 us.
//
// Round 7: NO LDS. Round 6 proved the dataflow (x row in VGPRs, W on the
// scalar pipe) but single-wave blocks left 2.3 waves/CU resident (7% occ) and
// every latency was exposed. LDS double-buffering fundamentally caps waves/CU
// (512 B/token), so x now loads STRAIGHT to VGPRs:
//  - 16 back-to-back global_load_dwordx4 per thread = whole row in flight at
//    once. Every touched 128B line is fully requested within the ~16-instr
//    burst (no cross-iteration reuse -> none of round-3's L1-thrash refetch).
//  - asm ""::: "memory" after the burst: loads are memory ops and cannot
//    legally sink below it (kills round-1's load-rematerialization).
//  - Outputs in 2 halves of 32 accumulators: stores burst 8 x dwordx4
//    back-to-back per half -> each 128B output line completes immediately
//    (kills round-1/2's partial-line write amplification).
//  - W/bias indices derive from loop constants only -> provably uniform ->
//    s_load through K$ (16 KB resident), parallel to the VALU (round-6 proof:
//    SGPR=112). 4 waves/SIMD now hide the s_load latency.
//  - No LDS => occupancy capped by VGPR only: ~100 regs -> 4-5 waves/SIMD,
//    ~16-20 waves/CU (7x round 6).

#define NDIM   64
#define TOKENS (1u << 20)

__global__ __launch_bounds__(256, 4) void poslin_relu_kernel(
    const float* __restrict__ x,
    const float* __restrict__ W,
    const float* __restrict__ bias,
    float* __restrict__ out)
{
    const size_t t = (size_t)blockIdx.x * blockDim.x + threadIdx.x;

    // ---- x row -> 64 VGPRs: 16 back-to-back dwordx4 ----
    const float4* __restrict__ xr = reinterpret_cast<const float4*>(x + t * NDIM);
    float xv[NDIM];
#pragma unroll
    for (int q = 0; q < 16; ++q) {
        const float4 v = xr[q];
        xv[4 * q + 0] = v.x;
        xv[4 * q + 1] = v.y;
        xv[4 * q + 2] = v.z;
        xv[4 * q + 3] = v.w;
    }
    // Loads may not sink below this point (compiler-level memory barrier).
    asm volatile("" ::: "memory");

    float* __restrict__ op = out + t * NDIM;

    // ---- two halves of 32 outputs; everything inside a half is fully
    // unrolled (static indices -> registers, rule #20); live regs ~100. ----
#pragma unroll 1
    for (int h = 0; h < 2; ++h) {
        const int ob = h * 32;   // scalar loop var -> uniform W/bias indices

        float a[32];
#pragma unroll
        for (int o = 0; o < 32; ++o) a[o] = bias[ob + o];

#pragma unroll
        for (int og = 0; og < 8; ++og) {
            const float* __restrict__ w0 = W + (size_t)(ob + og * 4 + 0) * NDIM;
            const float* __restrict__ w1 = W + (size_t)(ob + og * 4 + 1) * NDIM;
            const float* __restrict__ w2 = W + (size_t)(ob + og * 4 + 2) * NDIM;
            const float* __restrict__ w3 = W + (size_t)(ob + og * 4 + 3) * NDIM;
#pragma unroll
            for (int k = 0; k < NDIM; ++k) {   // static index into xv
                const float xk = xv[k];
                a[og * 4 + 0] = fmaf(xk, w0[k], a[og * 4 + 0]);
                a[og * 4 + 1] = fmaf(xk, w1[k], a[og * 4 + 1]);
                a[og * 4 + 2] = fmaf(xk, w2[k], a[og * 4 + 2]);
                a[og * 4 + 3] = fmaf(xk, w3[k], a[og * 4 + 3]);
            }
        }

        // ReLU + store burst: 8 x dwordx4 back-to-back = this half's full
        // 128B line per lane completed within ~8 instructions.
#pragma unroll
        for (int c = 0; c < 8; ++c) {
            float4 v;
            v.x = fmaxf(a[4 * c + 0], 0.0f);
            v.y = fmaxf(a[4 * c + 1], 0.0f);
            v.z = fmaxf(a[4 * c + 2], 0.0f);
            v.w = fmaxf(a[4 * c + 3], 0.0f);
            reinterpret_cast<float4*>(op + ob)[c] = v;
        }
    }
}

extern "C" void kernel_launch(void* const* d_in, const int* in_sizes, int n_in,
                              void* d_out, int out_size, void* d_ws, size_t ws_size,
                              hipStream_t stream) {
    const float* x    = (const float*)d_in[0];
    const float* W    = (const float*)d_in[1];
    const float* bias = (const float*)d_in[2];
    float* out        = (float*)d_out;

    const int block = 256;
    const int grid  = (int)(TOKENS / block);   // 4096 blocks, one shot
    poslin_relu_kernel<<<grid, block, 0, stream>>>(x, W, bias, out);
}

// Round 8
// 175.311 us; speedup vs baseline: 21.3840x; 1.5467x over previous
//
#include <hip/hip_runtime.h>

// PositionLinear + ReLU: out[t,:] = relu(W @ x[t,:] + b)
// x: [1M][64] f32, W: [64][64] f32, b: [64], out: [1M][64] f32.
// HBM floor ~536 MB @ ~6.3 TB/s => ~85 us. FMA floor 8.6 GFLOP @ 157 TF => ~55 us.
//
// Round 8 = round 7 + the missing regalloc knob.
// Root cause of rounds 1/2/7: __launch_bounds__ only sets MIN waves/EU; the
// backend still chased MAX occupancy (VGPR=36/56/40), splitting xv/acc and
// sinking stores into the compute -> fragmented 16B stores -> ~2x write
// amplification (WRITE 550-625 MB) + extra VALU work. Rounds where the store
// burst survived (3/4/6) all show WRITE ~= 262-292 MB.
// Fix: amdgpu_waves_per_eu(4,4) pins MAX occupancy = 4 waves/EU -> extra
// occupancy is worthless to the allocator -> it keeps the ~104-reg tile.
// Plus an asm memory barrier immediately before each store burst: stores
// cannot hoist above it, so all 32 accumulators are live there and the 8
// dwordx4 issue back-to-back (full 128B line completed within 8 instrs).
//
// Decisive check: VGPR_Count ~100-128. If still <=64, the knob failed ->
// switch to persistent-W outer-product formulation (x on scalar pipe).

#define NDIM   64
#define TOKENS (1u << 20)

__global__
__attribute__((amdgpu_flat_work_group_size(256, 256), amdgpu_waves_per_eu(4, 4)))
void poslin_relu_kernel(
    const float* __restrict__ x,
    const float* __restrict__ W,
    const float* __restrict__ bias,
    float* __restrict__ out)
{
    const size_t t = (size_t)blockIdx.x * blockDim.x + threadIdx.x;

    // ---- x row -> 64 VGPRs: 16 back-to-back dwordx4 (lines fully requested
    // within the burst window -> MSHR-merged, one HBM fetch per line). ----
    const float4* __restrict__ xr = reinterpret_cast<const float4*>(x + t * NDIM);
    float xv[NDIM];
#pragma unroll
    for (int q = 0; q < 16; ++q) {
        const float4 v = xr[q];
        xv[4 * q + 0] = v.x;
        xv[4 * q + 1] = v.y;
        xv[4 * q + 2] = v.z;
        xv[4 * q + 3] = v.w;
    }
    // Loads cannot sink below this point.
    asm volatile("" ::: "memory");

    float* __restrict__ op = out + t * NDIM;

    // ---- two halves of 32 outputs; h is a uniform loop var, so every
    // W/bias index is wave-uniform -> scalar s_load through K$ (16 KB,
    // resident), parallel to the VALU. All xv/acc indices static. ----
#pragma unroll 1
    for (int h = 0; h < 2; ++h) {
        const int ob = h * 32;

        float a[32];
#pragma unroll
        for (int o = 0; o < 32; ++o) a[o] = bias[ob + o];

#pragma unroll
        for (int og = 0; og < 8; ++og) {
            const float* __restrict__ w0 = W + (size_t)(ob + og * 4 + 0) * NDIM;
            const float* __restrict__ w1 = W + (size_t)(ob + og * 4 + 1) * NDIM;
            const float* __restrict__ w2 = W + (size_t)(ob + og * 4 + 2) * NDIM;
            const float* __restrict__ w3 = W + (size_t)(ob + og * 4 + 3) * NDIM;
#pragma unroll
            for (int k = 0; k < NDIM; ++k) {   // static index into xv
                const float xk = xv[k];
                a[og * 4 + 0] = fmaf(xk, w0[k], a[og * 4 + 0]);
                a[og * 4 + 1] = fmaf(xk, w1[k], a[og * 4 + 1]);
                a[og * 4 + 2] = fmaf(xk, w2[k], a[og * 4 + 2]);
                a[og * 4 + 3] = fmaf(xk, w3[k], a[og * 4 + 3]);
            }
        }

        // Stores cannot hoist above this barrier -> all 32 acc live here ->
        // 8 dwordx4 issue back-to-back (no fragmentation across compute).
        asm volatile("" ::: "memory");
#pragma unroll
        for (int c = 0; c < 8; ++c) {
            float4 v;
            v.x = fmaxf(a[4 * c + 0], 0.0f);
            v.y = fmaxf(a[4 * c + 1], 0.0f);
            v.z = fmaxf(a[4 * c + 2], 0.0f);
            v.w = fmaxf(a[4 * c + 3], 0.0f);
            reinterpret_cast<float4*>(op + ob)[c] = v;
        }
    }
}

extern "C" void kernel_launch(void* const* d_in, const int* in_sizes, int n_in,
                              void* d_out, int out_size, void* d_ws, size_t ws_size,
                              hipStream_t stream) {
    const float* x    = (const float*)d_in[0];
    const float* W    = (const float*)d_in[1];
    const float* bias = (const float*)d_in[2];
    float* out        = (float*)d_out;

    const int block = 256;
    const int grid  = (int)(TOKENS / block);   // 4096 blocks, one shot
    poslin_relu_kernel<<<grid, block, 0, stream>>>(x, W, bias, out);
}

// Round 10
// 107.367 us; speedup vs baseline: 34.9160x; 1.6328x over previous
//
#include <hip/hip_runtime.h>

// PositionLinear + ReLU via MFMA: out[t,:] = relu(W @ x[t,:] + b)
// x: [1M][64] f32, W: [64][64] f32, b: [64], out: [1M][64] f32.
// HBM floor ~536 MB @ ~6.3 TB/s => ~85 us.
//
// Round 10 = round 9 (fp16 hi/lo split MFMA GEMM) with the macro-pasting
// build bug fixed (bn##3.x lexed 3.x as one pp-number). Buffers are now
// float4[4] arrays with static indices (registers, rule #20); BODY/LOADX
// are inline functions.
//
// Math: x = xh + xl (RN f16 pair), W = Wh + Wl; x.w ~= Ah*Bh + Ah*Bl + Al*Bh
// (dropped Al*Bl <= 2^-22 |x.w|); products exact in f32, f32 accumulation ->
// fp32-level accuracy. 24 MFMA + ~110 VALU per 16-token tile => compute is
// ~8 us/SIMD; kernel should be purely memory-bound.
//
// Fragment layouts (16x16x32, C/D verified m89):
//   A (16x32): row m = lane&15, k = (lane>>4)*8 + j (+32 for k-half 1)
//   B (32x16): col n = lane&15, same k mapping
//   D (16x16): col n = lane&15, row m = (lane>>4)*4 + reg
// B = W^T: lane reads W row (nt*16 + lane&15), 8 consecutive floats per
// k-half. Persistent grid 768x4 waves; W fragments built once; x prefetch
// depth 1 in registers. No LDS, no barriers.

typedef _Float16 half8   __attribute__((ext_vector_type(8)));
typedef float    floatx4 __attribute__((ext_vector_type(4)));

#define NDIM   64
#define TOKENS (1u << 20)
#define TILES  (TOKENS / 16)        // 65536 tiles of 16 tokens
#define NBLK   768
#define WPB    4
#define NWAVES (NBLK * WPB)         // 3072

__device__ __forceinline__ void split8(const float v[8], half8& hi, half8& lo) {
#pragma unroll
    for (int j = 0; j < 8; ++j) {
        const _Float16 h = (_Float16)v[j];
        hi[j] = h;
        lo[j] = (_Float16)(v[j] - (float)h);   // exact residual
    }
}

struct Frag {
    half8 Bh[4][2], Bl[4][2];
    float bv[4];
};

__device__ __forceinline__ void loadx(float4 (&b)[4], const float* __restrict__ x,
                                      unsigned ti, int fr, int kg) {
    const float* xp = x + ((size_t)ti * 16 + fr) * NDIM + kg * 8;
    b[0] = *reinterpret_cast<const float4*>(xp);
    b[1] = *reinterpret_cast<const float4*>(xp + 4);
    b[2] = *reinterpret_cast<const float4*>(xp + 32);
    b[3] = *reinterpret_cast<const float4*>(xp + 36);
}

__device__ __forceinline__ void body(const float4 (&b)[4], const Frag& f,
                                     float* __restrict__ out, unsigned ti,
                                     int fr, int kg) {
    const float cva[8] = {b[0].x, b[0].y, b[0].z, b[0].w,
                          b[1].x, b[1].y, b[1].z, b[1].w};
    const float cvb[8] = {b[2].x, b[2].y, b[2].z, b[2].w,
                          b[3].x, b[3].y, b[3].z, b[3].w};
    half8 Ah0, Al0, Ah1, Al1;
    split8(cva, Ah0, Al0);
    split8(cvb, Ah1, Al1);

    floatx4 acc[4];
#pragma unroll
    for (int nt = 0; nt < 4; ++nt)
        acc[nt] = (floatx4){f.bv[nt], f.bv[nt], f.bv[nt], f.bv[nt]};
#pragma unroll
    for (int nt = 0; nt < 4; ++nt) {
        acc[nt] = __builtin_amdgcn_mfma_f32_16x16x32_f16(Ah0, f.Bl[nt][0], acc[nt], 0, 0, 0);
        acc[nt] = __builtin_amdgcn_mfma_f32_16x16x32_f16(Al0, f.Bh[nt][0], acc[nt], 0, 0, 0);
        acc[nt] = __builtin_amdgcn_mfma_f32_16x16x32_f16(Ah0, f.Bh[nt][0], acc[nt], 0, 0, 0);
        acc[nt] = __builtin_amdgcn_mfma_f32_16x16x32_f16(Ah1, f.Bl[nt][1], acc[nt], 0, 0, 0);
        acc[nt] = __builtin_amdgcn_mfma_f32_16x16x32_f16(Al1, f.Bh[nt][1], acc[nt], 0, 0, 0);
        acc[nt] = __builtin_amdgcn_mfma_f32_16x16x32_f16(Ah1, f.Bh[nt][1], acc[nt], 0, 0, 0);
    }

    // D: col n = fr, row m = kg*4 + j. Four lanes with the same fr write 4
    // consecutive rows; per (j, nt) a wave's 16 fr-lanes write 64B runs.
    float* op = out + ((size_t)ti * 16 + kg * 4) * NDIM + fr;
#pragma unroll
    for (int j = 0; j < 4; ++j) {
#pragma unroll
        for (int nt = 0; nt < 4; ++nt)
            op[j * NDIM + nt * 16] = fmaxf(acc[nt][j], 0.0f);
    }
}

__global__
__attribute__((amdgpu_flat_work_group_size(256, 256), amdgpu_waves_per_eu(2, 3)))
void poslin_relu_mfma(const float* __restrict__ x,
                      const float* __restrict__ W,
                      const float* __restrict__ bias,
                      float* __restrict__ out)
{
    const int tid  = threadIdx.x;
    const int wv   = tid >> 6;
    const int lane = tid & 63;
    const int fr   = lane & 15;   // free-dim index (m for A, n for B/D)
    const int kg   = lane >> 4;   // k base = kg*8 (+32 per k-half)

    // ---- B fragments: W^T -> registers once, hi/lo f16 split ----
    Frag f;
#pragma unroll
    for (int nt = 0; nt < 4; ++nt) {
#pragma unroll
        for (int kh = 0; kh < 2; ++kh) {
            const float* wp = W + (size_t)(nt * 16 + fr) * NDIM + kg * 8 + kh * 32;
            const float4 a = *reinterpret_cast<const float4*>(wp);
            const float4 c = *reinterpret_cast<const float4*>(wp + 4);
            const float tmp[8] = {a.x, a.y, a.z, a.w, c.x, c.y, c.z, c.w};
            split8(tmp, f.Bh[nt][kh], f.Bl[nt][kh]);
        }
    }
#pragma unroll
    for (int nt = 0; nt < 4; ++nt) f.bv[nt] = bias[nt * 16 + fr];

    // ---- persistent tile stream, register double-buffer, prefetch 1 ----
    float4 xa[4], xb[4];
    unsigned t = (unsigned)blockIdx.x * WPB + wv;
    if (t >= TILES) return;
    loadx(xa, x, t, fr, kg);
    while (true) {
        const unsigned tn = t + NWAVES;
        if (tn < TILES) loadx(xb, x, tn, fr, kg);
        body(xa, f, out, t, fr, kg);
        if (tn >= TILES) break;
        t = tn;
        const unsigned tm = t + NWAVES;
        if (tm < TILES) loadx(xa, x, tm, fr, kg);
        body(xb, f, out, t, fr, kg);
        if (tm >= TILES) break;
        t = tm;
    }
}

extern "C" void kernel_launch(void* const* d_in, const int* in_sizes, int n_in,
                              void* d_out, int out_size, void* d_ws, size_t ws_size,
                              hipStream_t stream) {
    const float* x    = (const float*)d_in[0];
    const float* W    = (const float*)d_in[1];
    const float* bias = (const float*)d_in[2];
    float* out        = (float*)d_out;

    poslin_relu_mfma<<<NBLK, 256, 0, stream>>>(x, W, bias, out);
}